// Round 8
// baseline (258.333 us; speedup 1.0000x reference)
//
#include <hip/hip_runtime.h>

// SimpleSAGE v3. v2 post-mortem: k_mark at 72.7us, 1.1% HBM, 0.7% VALU ->
// serialized on a single hot append counter (blocking wave-aggregated
// atomicAdd+shfl, same-line RMWs can't pipeline) plus a 200KB flag gather
// per edge. v3: arithmetic center test (cpos is 2KB, L1), 64-way lane-sharded
// append counters (64B-padded lines, per-shard 256-entry segments), frontier
// bitmap (6.25KB, L1-resident) for the aggregation scan.

constexpr int NN  = 50000;
constexpr int NG  = 500;
constexpr int NPG = 100;
constexpr int NE  = 800000;   // % 64 == 0
constexpr int D   = 64;
constexpr int NSH = 64;       // shards (= lanes)
constexpr int SEG = 256;      // entries per shard
constexpr int CAP = NSH * SEG;  // 16384 slot/edge capacity (hard max ~8.5k used)
constexpr int CPAD = 16;      // counter pad: 16 ints = 64B line per shard

// ---- workspace layout ----
constexpr size_t OFF_AGG2  = 0;                                   // NG*D f32   (zeroed)
constexpr size_t OFF_BMP   = OFF_AGG2 + (size_t)NG * D * 4;       // 2048 u32   (zeroed)
constexpr size_t OFF_DEGC  = OFF_BMP + 2048 * 4;                  // CAP i32    (zeroed)
constexpr size_t OFF_CNTE  = OFF_DEGC + (size_t)CAP * 4;          // NSH*CPAD   (zeroed)
constexpr size_t OFF_CNTS  = OFF_CNTE + (size_t)NSH * CPAD * 4;   // NSH*CPAD   (zeroed)
constexpr size_t ZERO_BYTES = OFF_CNTS + (size_t)NSH * CPAD * 4 - OFF_AGG2;
constexpr size_t OFF_AGGC  = OFF_CNTS + (size_t)NSH * CPAD * 4;   // CAP*D f32  (rows zeroed lazily)
constexpr size_t OFF_SLOT  = OFF_AGGC + (size_t)CAP * D * 4;      // NN i32     (frontier entries only)
constexpr size_t OFF_NLIST = OFF_SLOT + (size_t)NN * 4;           // CAP i32    (valid slots only)
constexpr size_t OFF_ELIST = OFF_NLIST + (size_t)CAP * 4;         // CAP int2

__global__ void k_init(const int* __restrict__ cpos, unsigned int* __restrict__ bmp) {
  int g = blockIdx.x * blockDim.x + threadIdx.x;
  if (g < NG) {
    int c = g * NPG + cpos[g];
    atomicOr(&bmp[c >> 5], 1u << (c & 31));
  }
}

// Scan edges; center test is ARITHMETIC (cpos[d/100]==d%100, no big gather).
// Matched lanes append (src,dst) to their lane's shard segment (per-lane
// atomic on a private 64B line -> no cross-wave hot counter) and OR the src
// into the frontier bitmap.
__global__ void k_mark(const int* __restrict__ src, const int* __restrict__ dst,
                       const int* __restrict__ cpos, unsigned int* __restrict__ bmp,
                       int2* __restrict__ elist, int* __restrict__ cntE) {
  int lane = threadIdx.x & 63;
  int wid  = (blockIdx.x * blockDim.x + threadIdx.x) >> 6;
  int nw   = (gridDim.x * blockDim.x) >> 6;
  for (int base = wid * 64; base < NE; base += nw * 64) {
    int e = base + lane;
    int d = dst[e];
    int g = d / NPG;
    bool m = (g * NPG + cpos[g] == d);
    if (m) {
      int s = src[e];
      atomicOr(&bmp[s >> 5], 1u << (s & 31));
      int idx = atomicAdd(&cntE[lane * CPAD], 1);
      if (idx < SEG) elist[lane * SEG + idx] = make_int2(s, d);
    }
  }
}

// Assign sharded compact slots to bitmap nodes; zero their aggC rows.
// slot = lane*SEG + idx; validity later tested as (slot&255) < cntS[slot>>8].
__global__ void k_compact(const unsigned int* __restrict__ bmp, int* __restrict__ slot,
                          int* __restrict__ nodelist, float* __restrict__ aggC,
                          int* __restrict__ cntS) {
  int v = blockIdx.x * blockDim.x + threadIdx.x;
  int lane = threadIdx.x & 63;
  if (v >= NN) return;
  if ((bmp[v >> 5] >> (v & 31)) & 1) {
    int idx = atomicAdd(&cntS[lane * CPAD], 1);
    if (idx < SEG) {
      int sl = lane * SEG + idx;
      slot[v] = sl;
      nodelist[sl] = v;
      float4 z = make_float4(0.f, 0.f, 0.f, 0.f);
      float4* row = (float4*)&aggC[(size_t)sl * D];
#pragma unroll
      for (int i = 0; i < D / 4; i++) row[i] = z;
    }
  }
}

// Scan edges; bitmap (L1-resident 6.25KB) filters frontier dsts; matched
// lanes gather slot+src in parallel, count degree, then the wave round-robins
// the matched edges doing coalesced 256B row gather + row atomicAdd.
__global__ void k_agg2(const int* __restrict__ src, const int* __restrict__ dst,
                       const unsigned int* __restrict__ bmp, const int* __restrict__ slot,
                       const float* __restrict__ x, float* __restrict__ aggC,
                       int* __restrict__ degC) {
  int lane = threadIdx.x & 63;
  int wid  = (blockIdx.x * blockDim.x + threadIdx.x) >> 6;
  int nw   = (gridDim.x * blockDim.x) >> 6;
  for (int base = wid * 64; base < NE; base += nw * 64) {
    int e = base + lane;
    int d = dst[e];
    bool m = (bmp[d >> 5] >> (d & 31)) & 1;
    int s = 0, sl = 0;
    if (m) {
      s  = src[e];
      sl = slot[d];
      atomicAdd(&degC[sl], 1);
    }
    unsigned long long bal = __ballot(m);
    while (bal) {
      int b = __ffsll(bal) - 1;
      bal &= bal - 1;
      int ss  = __shfl(s, b);
      int sld = __shfl(sl, b);
      atomicAdd(&aggC[(size_t)sld * D + lane], x[(size_t)ss * D + lane]);
    }
  }
}

// h1[slot] = relu(Wl1*(aggC/deg) + bl1 + Wr1*x[node]) in-place, valid slots only.
__global__ void k_sage1(const float* __restrict__ x, const int* __restrict__ nodelist,
                        const int* __restrict__ degC, float* __restrict__ aggC,
                        const float* __restrict__ Wl, const float* __restrict__ bl,
                        const float* __restrict__ Wr, const int* __restrict__ cntS) {
  __shared__ float sWl[D * 65];
  __shared__ float sWr[D * 65];
  __shared__ float sbl[D];
  int tid = threadIdx.x;
  for (int i = tid; i < D * D; i += blockDim.x) {
    int r = i >> 6, c = i & 63;
    sWl[r * 65 + c] = Wl[i];
    sWr[r * 65 + c] = Wr[i];
  }
  if (tid < D) sbl[tid] = bl[tid];
  __syncthreads();

  int lane = tid & 63;
  int wid  = (blockIdx.x * blockDim.x + tid) >> 6;
  int nw   = (gridDim.x * blockDim.x) >> 6;
  for (int sl = wid; sl < CAP; sl += nw) {
    int shard = sl >> 8, idx = sl & (SEG - 1);
    int n = cntS[shard * CPAD];
    if (idx >= (n > SEG ? SEG : n)) continue;   // wave-uniform
    int v = nodelist[sl];
    float dg = (float)degC[sl];
    if (dg < 1.f) dg = 1.f;
    float m  = aggC[(size_t)sl * D + lane] / dg;
    float xv = x[(size_t)v * D + lane];
    float h  = sbl[lane];
#pragma unroll
    for (int k = 0; k < D; k++) {
      h += sWl[lane * 65 + k] * __shfl(m, k) + sWr[lane * 65 + k] * __shfl(xv, k);
    }
    aggC[(size_t)sl * D + lane] = fmaxf(h, 0.f);
  }
}

// Center-edge list: agg2[graph(dst)] += h1[slot(src)].
__global__ void k_agg1(const int2* __restrict__ elist, const int* __restrict__ slot,
                       const float* __restrict__ aggC, float* __restrict__ agg2,
                       const int* __restrict__ cntE) {
  int lane = threadIdx.x & 63;
  int wid  = (blockIdx.x * blockDim.x + threadIdx.x) >> 6;
  int nw   = (gridDim.x * blockDim.x) >> 6;
  for (int t = wid; t < CAP; t += nw) {
    int shard = t >> 8, idx = t & (SEG - 1);
    int n = cntE[shard * CPAD];
    if (idx >= (n > SEG ? SEG : n)) continue;   // wave-uniform
    int2 ed = elist[t];
    int sl = slot[ed.x];
    int g  = ed.y / NPG;
    atomicAdd(&agg2[(size_t)g * D + lane], aggC[(size_t)sl * D + lane]);
  }
}

__global__ void k_final(const float* __restrict__ aggC, const float* __restrict__ agg2,
                        const int* __restrict__ degC, const int* __restrict__ slot,
                        const int* __restrict__ cpos, const float* __restrict__ Wl2,
                        const float* __restrict__ bl2, const float* __restrict__ Wr2,
                        const float* __restrict__ Wlin, const float* __restrict__ blin,
                        float* __restrict__ out) {
  int lane = threadIdx.x & 63;
  int g = (blockIdx.x * blockDim.x + threadIdx.x) >> 6;
  if (g >= NG) return;
  int c  = g * NPG + cpos[g];
  int sl = slot[c];
  float dg = (float)degC[sl];
  if (dg < 1.f) dg = 1.f;
  float m  = agg2[(size_t)g * D + lane] / dg;
  float hc = aggC[(size_t)sl * D + lane];
  float h  = bl2[lane];
#pragma unroll
  for (int k = 0; k < D; k++) {
    h += Wl2[lane * D + k] * __shfl(m, k) + Wr2[lane * D + k] * __shfl(hc, k);
  }
  h = fmaxf(h, 0.f);
  float p = Wlin[lane] * h;
#pragma unroll
  for (int off = 32; off; off >>= 1) p += __shfl_down(p, off);
  if (lane == 0) out[g] = p + blin[0];
}

extern "C" void kernel_launch(void* const* d_in, const int* in_sizes, int n_in,
                              void* d_out, int out_size, void* d_ws, size_t ws_size,
                              hipStream_t stream) {
  const float* x    = (const float*)d_in[0];
  const int*   ei   = (const int*)d_in[1];
  const int*   srcI = ei;          // edge_index[0]
  const int*   dstI = ei + NE;     // edge_index[1]
  const int*   cpos = (const int*)d_in[3];
  const float* Wl1  = (const float*)d_in[4];
  const float* bl1  = (const float*)d_in[5];
  const float* Wr1  = (const float*)d_in[6];
  const float* Wl2  = (const float*)d_in[7];
  const float* bl2  = (const float*)d_in[8];
  const float* Wr2  = (const float*)d_in[9];
  const float* Wlin = (const float*)d_in[10];
  const float* blin = (const float*)d_in[11];
  float* out = (float*)d_out;

  char* ws = (char*)d_ws;
  float*        agg2 = (float*)(ws + OFF_AGG2);
  unsigned int* bmp  = (unsigned int*)(ws + OFF_BMP);
  int*          degC = (int*)(ws + OFF_DEGC);
  int*          cntE = (int*)(ws + OFF_CNTE);
  int*          cntS = (int*)(ws + OFF_CNTS);
  float*        aggC = (float*)(ws + OFF_AGGC);
  int*          slot = (int*)(ws + OFF_SLOT);
  int*          nlst = (int*)(ws + OFF_NLIST);
  int2*         elst = (int2*)(ws + OFF_ELIST);

  hipMemsetAsync(ws + OFF_AGG2, 0, ZERO_BYTES, stream);
  k_init<<<2, 256, 0, stream>>>(cpos, bmp);
  k_mark<<<2048, 256, 0, stream>>>(srcI, dstI, cpos, bmp, elst, cntE);
  k_compact<<<(NN + 255) / 256, 256, 0, stream>>>(bmp, slot, nlst, aggC, cntS);
  k_agg2<<<2048, 256, 0, stream>>>(srcI, dstI, bmp, slot, x, aggC, degC);
  k_sage1<<<128, 256, 0, stream>>>(x, nlst, degC, aggC, Wl1, bl1, Wr1, cntS);
  k_agg1<<<128, 256, 0, stream>>>(elst, slot, aggC, agg2, cntE);
  k_final<<<(NG * 64 + 255) / 256, 256, 0, stream>>>(aggC, agg2, degC, slot, cpos,
                                                     Wl2, bl2, Wr2, Wlin, blin, out);
}

// Round 9
// 196.038 us; speedup vs baseline: 1.3178x; 1.3178x over previous
//
#include <hip/hip_runtime.h>

// SimpleSAGE v4. v3 post-mortem: k_sage1 at 81us, occ 3%, VALU 3% ->
// latency-bound: 128-block grid left half the CUs empty and each wave
// serially chewed ~32 slots with a 128-deep shfl+FMA dependent chain.
// v4: k_sage1 rewritten -- 512 blocks (8 slots/wave, 8+ waves/CU),
// per-lane weight rows in REGISTERS (no LDS), 4-way split accumulators.
// Everything else identical to v3 (sharded counters, bitmap frontier).

constexpr int NN  = 50000;
constexpr int NG  = 500;
constexpr int NPG = 100;
constexpr int NE  = 800000;   // % 64 == 0
constexpr int D   = 64;
constexpr int NSH = 64;       // shards (= lanes)
constexpr int SEG = 256;      // entries per shard
constexpr int CAP = NSH * SEG;  // 16384 slot/edge capacity (~8.5k used)
constexpr int CPAD = 16;      // counter pad: 16 ints = 64B line per shard

// ---- workspace layout ----
constexpr size_t OFF_AGG2  = 0;                                   // NG*D f32   (zeroed)
constexpr size_t OFF_BMP   = OFF_AGG2 + (size_t)NG * D * 4;       // 2048 u32   (zeroed)
constexpr size_t OFF_DEGC  = OFF_BMP + 2048 * 4;                  // CAP i32    (zeroed)
constexpr size_t OFF_CNTE  = OFF_DEGC + (size_t)CAP * 4;          // NSH*CPAD   (zeroed)
constexpr size_t OFF_CNTS  = OFF_CNTE + (size_t)NSH * CPAD * 4;   // NSH*CPAD   (zeroed)
constexpr size_t ZERO_BYTES = OFF_CNTS + (size_t)NSH * CPAD * 4 - OFF_AGG2;
constexpr size_t OFF_AGGC  = OFF_CNTS + (size_t)NSH * CPAD * 4;   // CAP*D f32  (rows zeroed lazily)
constexpr size_t OFF_SLOT  = OFF_AGGC + (size_t)CAP * D * 4;      // NN i32     (frontier entries only)
constexpr size_t OFF_NLIST = OFF_SLOT + (size_t)NN * 4;           // CAP i32    (valid slots only)
constexpr size_t OFF_ELIST = OFF_NLIST + (size_t)CAP * 4;         // CAP int2

__global__ void k_init(const int* __restrict__ cpos, unsigned int* __restrict__ bmp) {
  int g = blockIdx.x * blockDim.x + threadIdx.x;
  if (g < NG) {
    int c = g * NPG + cpos[g];
    atomicOr(&bmp[c >> 5], 1u << (c & 31));
  }
}

// Scan edges; center test is ARITHMETIC (cpos[d/100]==d%100, no big gather).
// Matched lanes append (src,dst) to their lane's shard segment (per-lane
// atomic on a private 64B line) and OR the src into the frontier bitmap.
__global__ void k_mark(const int* __restrict__ src, const int* __restrict__ dst,
                       const int* __restrict__ cpos, unsigned int* __restrict__ bmp,
                       int2* __restrict__ elist, int* __restrict__ cntE) {
  int lane = threadIdx.x & 63;
  int wid  = (blockIdx.x * blockDim.x + threadIdx.x) >> 6;
  int nw   = (gridDim.x * blockDim.x) >> 6;
  for (int base = wid * 64; base < NE; base += nw * 64) {
    int e = base + lane;
    int d = dst[e];
    int g = d / NPG;
    bool m = (g * NPG + cpos[g] == d);
    if (m) {
      int s = src[e];
      atomicOr(&bmp[s >> 5], 1u << (s & 31));
      int idx = atomicAdd(&cntE[lane * CPAD], 1);
      if (idx < SEG) elist[lane * SEG + idx] = make_int2(s, d);
    }
  }
}

// Assign sharded compact slots to bitmap nodes; zero their aggC rows.
__global__ void k_compact(const unsigned int* __restrict__ bmp, int* __restrict__ slot,
                          int* __restrict__ nodelist, float* __restrict__ aggC,
                          int* __restrict__ cntS) {
  int v = blockIdx.x * blockDim.x + threadIdx.x;
  int lane = threadIdx.x & 63;
  if (v >= NN) return;
  if ((bmp[v >> 5] >> (v & 31)) & 1) {
    int idx = atomicAdd(&cntS[lane * CPAD], 1);
    if (idx < SEG) {
      int sl = lane * SEG + idx;
      slot[v] = sl;
      nodelist[sl] = v;
      float4 z = make_float4(0.f, 0.f, 0.f, 0.f);
      float4* row = (float4*)&aggC[(size_t)sl * D];
#pragma unroll
      for (int i = 0; i < D / 4; i++) row[i] = z;
    }
  }
}

// Scan edges; bitmap (L1-resident 6.25KB) filters frontier dsts; wave
// round-robins matched edges: coalesced 256B x-row gather + row atomicAdd.
__global__ void k_agg2(const int* __restrict__ src, const int* __restrict__ dst,
                       const unsigned int* __restrict__ bmp, const int* __restrict__ slot,
                       const float* __restrict__ x, float* __restrict__ aggC,
                       int* __restrict__ degC) {
  int lane = threadIdx.x & 63;
  int wid  = (blockIdx.x * blockDim.x + threadIdx.x) >> 6;
  int nw   = (gridDim.x * blockDim.x) >> 6;
  for (int base = wid * 64; base < NE; base += nw * 64) {
    int e = base + lane;
    int d = dst[e];
    bool m = (bmp[d >> 5] >> (d & 31)) & 1;
    int s = 0, sl = 0;
    if (m) {
      s  = src[e];
      sl = slot[d];
      atomicAdd(&degC[sl], 1);
    }
    unsigned long long bal = __ballot(m);
    while (bal) {
      int b = __ffsll(bal) - 1;
      bal &= bal - 1;
      int ss  = __shfl(s, b);
      int sld = __shfl(sl, b);
      atomicAdd(&aggC[(size_t)sld * D + lane], x[(size_t)ss * D + lane]);
    }
  }
}

// h1[slot] = relu(Wl1*(aggC/deg) + bl1 + Wr1*x[node]) in-place.
// One wave per 8 slots; per-lane weight ROWS held in registers (32 float4);
// 4-way split accumulators to shorten the FMA dependency chain.
__global__ __launch_bounds__(256, 2)
void k_sage1(const float* __restrict__ x, const int* __restrict__ nodelist,
             const int* __restrict__ degC, float* __restrict__ aggC,
             const float* __restrict__ Wl, const float* __restrict__ bl,
             const float* __restrict__ Wr, const int* __restrict__ cntS) {
  int tid  = threadIdx.x;
  int lane = tid & 63;
  float4 wl[16], wr[16];
  const float4* Wl4 = (const float4*)(Wl + (size_t)lane * D);
  const float4* Wr4 = (const float4*)(Wr + (size_t)lane * D);
#pragma unroll
  for (int i = 0; i < 16; i++) { wl[i] = Wl4[i]; wr[i] = Wr4[i]; }
  float bias = bl[lane];

  int wid = (blockIdx.x * blockDim.x + tid) >> 6;
  int nw  = (gridDim.x * blockDim.x) >> 6;
  for (int sl = wid; sl < CAP; sl += nw) {
    int shard = sl >> 8, idx = sl & (SEG - 1);
    int n = cntS[shard * CPAD];
    if (idx >= (n > SEG ? SEG : n)) continue;   // wave-uniform
    int v = nodelist[sl];
    float dg = (float)degC[sl];
    if (dg < 1.f) dg = 1.f;
    float m  = aggC[(size_t)sl * D + lane] / dg;
    float xv = x[(size_t)v * D + lane];
    float h0 = 0.f, h1 = 0.f, h2 = 0.f, h3 = 0.f;
#pragma unroll
    for (int k = 0; k < D; k += 2) {
      float mk0 = __shfl(m, k);
      float xk0 = __shfl(xv, k);
      float mk1 = __shfl(m, k + 1);
      float xk1 = __shfl(xv, k + 1);
      float a0 = ((const float*)&wl[k >> 2])[k & 3];
      float b0 = ((const float*)&wr[k >> 2])[k & 3];
      float a1 = ((const float*)&wl[(k + 1) >> 2])[(k + 1) & 3];
      float b1 = ((const float*)&wr[(k + 1) >> 2])[(k + 1) & 3];
      h0 += a0 * mk0;
      h1 += b0 * xk0;
      h2 += a1 * mk1;
      h3 += b1 * xk1;
    }
    float h = bias + ((h0 + h2) + (h1 + h3));
    aggC[(size_t)sl * D + lane] = fmaxf(h, 0.f);
  }
}

// Center-edge list: agg2[graph(dst)] += h1[slot(src)].
__global__ void k_agg1(const int2* __restrict__ elist, const int* __restrict__ slot,
                       const float* __restrict__ aggC, float* __restrict__ agg2,
                       const int* __restrict__ cntE) {
  int lane = threadIdx.x & 63;
  int wid  = (blockIdx.x * blockDim.x + threadIdx.x) >> 6;
  int nw   = (gridDim.x * blockDim.x) >> 6;
  for (int t = wid; t < CAP; t += nw) {
    int shard = t >> 8, idx = t & (SEG - 1);
    int n = cntE[shard * CPAD];
    if (idx >= (n > SEG ? SEG : n)) continue;   // wave-uniform
    int2 ed = elist[t];
    int sl = slot[ed.x];
    int g  = ed.y / NPG;
    atomicAdd(&agg2[(size_t)g * D + lane], aggC[(size_t)sl * D + lane]);
  }
}

__global__ void k_final(const float* __restrict__ aggC, const float* __restrict__ agg2,
                        const int* __restrict__ degC, const int* __restrict__ slot,
                        const int* __restrict__ cpos, const float* __restrict__ Wl2,
                        const float* __restrict__ bl2, const float* __restrict__ Wr2,
                        const float* __restrict__ Wlin, const float* __restrict__ blin,
                        float* __restrict__ out) {
  int lane = threadIdx.x & 63;
  int g = (blockIdx.x * blockDim.x + threadIdx.x) >> 6;
  if (g >= NG) return;
  int c  = g * NPG + cpos[g];
  int sl = slot[c];
  float dg = (float)degC[sl];
  if (dg < 1.f) dg = 1.f;
  float m  = agg2[(size_t)g * D + lane] / dg;
  float hc = aggC[(size_t)sl * D + lane];
  float h  = bl2[lane];
#pragma unroll
  for (int k = 0; k < D; k++) {
    h += Wl2[lane * D + k] * __shfl(m, k) + Wr2[lane * D + k] * __shfl(hc, k);
  }
  h = fmaxf(h, 0.f);
  float p = Wlin[lane] * h;
#pragma unroll
  for (int off = 32; off; off >>= 1) p += __shfl_down(p, off);
  if (lane == 0) out[g] = p + blin[0];
}

extern "C" void kernel_launch(void* const* d_in, const int* in_sizes, int n_in,
                              void* d_out, int out_size, void* d_ws, size_t ws_size,
                              hipStream_t stream) {
  const float* x    = (const float*)d_in[0];
  const int*   ei   = (const int*)d_in[1];
  const int*   srcI = ei;          // edge_index[0]
  const int*   dstI = ei + NE;     // edge_index[1]
  const int*   cpos = (const int*)d_in[3];
  const float* Wl1  = (const float*)d_in[4];
  const float* bl1  = (const float*)d_in[5];
  const float* Wr1  = (const float*)d_in[6];
  const float* Wl2  = (const float*)d_in[7];
  const float* bl2  = (const float*)d_in[8];
  const float* Wr2  = (const float*)d_in[9];
  const float* Wlin = (const float*)d_in[10];
  const float* blin = (const float*)d_in[11];
  float* out = (float*)d_out;

  char* ws = (char*)d_ws;
  float*        agg2 = (float*)(ws + OFF_AGG2);
  unsigned int* bmp  = (unsigned int*)(ws + OFF_BMP);
  int*          degC = (int*)(ws + OFF_DEGC);
  int*          cntE = (int*)(ws + OFF_CNTE);
  int*          cntS = (int*)(ws + OFF_CNTS);
  float*        aggC = (float*)(ws + OFF_AGGC);
  int*          slot = (int*)(ws + OFF_SLOT);
  int*          nlst = (int*)(ws + OFF_NLIST);
  int2*         elst = (int2*)(ws + OFF_ELIST);

  hipMemsetAsync(ws + OFF_AGG2, 0, ZERO_BYTES, stream);
  k_init<<<2, 256, 0, stream>>>(cpos, bmp);
  k_mark<<<2048, 256, 0, stream>>>(srcI, dstI, cpos, bmp, elst, cntE);
  k_compact<<<(NN + 255) / 256, 256, 0, stream>>>(bmp, slot, nlst, aggC, cntS);
  k_agg2<<<2048, 256, 0, stream>>>(srcI, dstI, bmp, slot, x, aggC, degC);
  k_sage1<<<512, 256, 0, stream>>>(x, nlst, degC, aggC, Wl1, bl1, Wr1, cntS);
  k_agg1<<<256, 256, 0, stream>>>(elst, slot, aggC, agg2, cntE);
  k_final<<<(NG * 64 + 255) / 256, 256, 0, stream>>>(aggC, agg2, degC, slot, cpos,
                                                     Wl2, bl2, Wr2, Wlin, blin, out);
}

// Round 13
// 178.905 us; speedup vs baseline: 1.4440x; 1.0958x over previous
//
#include <hip/hip_runtime.h>

// SimpleSAGE v5. v4 post-mortem: k_agg2 45.6us with WRITE_SIZE=35.6MB ==
// 126k frontier-inbound edges x 256B row-atomicAdd (device-scope float
// atomics RMW at the coherence point -> memory-side write amplification;
// real dirty data ~2MB). v5 kills the atomic row table: k_fill appends
// 4B source-ids to per-slot buckets; k_sage1 fuses the mean-gather (bucket
// -> coalesced x-row gathers, 4-way ILP) with the register GEMV and writes
// h1 once. k_init folded into k_mark.

constexpr int NN  = 50000;
constexpr int NG  = 500;
constexpr int NPG = 100;
constexpr int NE  = 800000;   // % 64 == 0
constexpr int D   = 64;
constexpr int NSH = 64;       // shards (= lanes)
constexpr int SEG = 256;      // entries per shard
constexpr int CAP = NSH * SEG;  // 16384 slots (~8.5k used)
constexpr int CPAD = 16;      // 64B line per shard counter
constexpr int MAXDEG = 64;    // bucket capacity (mean deg 16, tail ~1e-20)

// ---- workspace layout ----
constexpr size_t OFF_AGG2  = 0;                                   // NG*D f32   (zeroed)
constexpr size_t OFF_BMP   = OFF_AGG2 + (size_t)NG * D * 4;       // 2048 u32   (zeroed)
constexpr size_t OFF_DEGC  = OFF_BMP + 2048 * 4;                  // CAP i32    (zeroed)
constexpr size_t OFF_CNTE  = OFF_DEGC + (size_t)CAP * 4;          // NSH*CPAD   (zeroed)
constexpr size_t OFF_CNTS  = OFF_CNTE + (size_t)NSH * CPAD * 4;   // NSH*CPAD   (zeroed)
constexpr size_t ZERO_BYTES = OFF_CNTS + (size_t)NSH * CPAD * 4 - OFF_AGG2;
constexpr size_t OFF_H1    = OFF_CNTS + (size_t)NSH * CPAD * 4;   // CAP*D f32  (write-once)
constexpr size_t OFF_SLOT  = OFF_H1 + (size_t)CAP * D * 4;        // NN i32     (frontier only)
constexpr size_t OFF_NLIST = OFF_SLOT + (size_t)NN * 4;           // CAP i32
constexpr size_t OFF_ELIST = OFF_NLIST + (size_t)CAP * 4;         // CAP int2
constexpr size_t OFF_BKT   = OFF_ELIST + (size_t)CAP * 8;         // CAP*MAXDEG i32

// Scan edges; arithmetic center test (cpos[d/100]==d%100). Matched lanes
// append (src,dst) to their lane's shard segment and OR src into the bitmap.
// First NG threads also set the center bits (folded k_init).
__global__ void k_mark(const int* __restrict__ src, const int* __restrict__ dst,
                       const int* __restrict__ cpos, unsigned int* __restrict__ bmp,
                       int2* __restrict__ elist, int* __restrict__ cntE) {
  int gid  = blockIdx.x * blockDim.x + threadIdx.x;
  if (gid < NG) {
    int c = gid * NPG + cpos[gid];
    atomicOr(&bmp[c >> 5], 1u << (c & 31));
  }
  int lane = threadIdx.x & 63;
  int wid  = gid >> 6;
  int nw   = (gridDim.x * blockDim.x) >> 6;
  for (int base = wid * 64; base < NE; base += nw * 64) {
    int e = base + lane;
    int d = dst[e];
    int g = d / NPG;
    bool m = (g * NPG + cpos[g] == d);
    if (m) {
      int s = src[e];
      atomicOr(&bmp[s >> 5], 1u << (s & 31));
      int idx = atomicAdd(&cntE[lane * CPAD], 1);
      if (idx < SEG) elist[lane * SEG + idx] = make_int2(s, d);
    }
  }
}

// Assign sharded compact slots to bitmap nodes.
__global__ void k_compact(const unsigned int* __restrict__ bmp, int* __restrict__ slot,
                          int* __restrict__ nodelist, int* __restrict__ cntS) {
  int v = blockIdx.x * blockDim.x + threadIdx.x;
  int lane = threadIdx.x & 63;
  if (v >= NN) return;
  if ((bmp[v >> 5] >> (v & 31)) & 1) {
    int idx = atomicAdd(&cntS[lane * CPAD], 1);
    if (idx < SEG) {
      int sl = lane * SEG + idx;
      slot[v] = sl;
      nodelist[sl] = v;
    }
  }
}

// Scan edges; bitmap filters frontier dsts; matched lanes append their
// src id (4B) to the dst-slot's bucket. No row atomics, no ballot loop.
__global__ void k_fill(const int* __restrict__ src, const int* __restrict__ dst,
                       const unsigned int* __restrict__ bmp, const int* __restrict__ slot,
                       int* __restrict__ bucket, int* __restrict__ degC) {
  int lane = threadIdx.x & 63;
  int wid  = (blockIdx.x * blockDim.x + threadIdx.x) >> 6;
  int nw   = (gridDim.x * blockDim.x) >> 6;
  for (int base = wid * 64; base < NE; base += nw * 64) {
    int e = base + lane;
    int d = dst[e];
    if ((bmp[d >> 5] >> (d & 31)) & 1) {
      int sl  = slot[d];
      int idx = atomicAdd(&degC[sl], 1);
      if (idx < MAXDEG) bucket[sl * MAXDEG + idx] = src[e];
    }
  }
}

// Fused: mean over bucket x-rows (4-way ILP gathers) + register GEMV.
// h1[sl] = relu(Wl1*(sum/deg) + bl1 + Wr1*x[v]), written once.
__global__ __launch_bounds__(256, 2)
void k_sage1(const float* __restrict__ x, const int* __restrict__ nodelist,
             const int* __restrict__ degC, const int* __restrict__ bucket,
             float* __restrict__ h1out,
             const float* __restrict__ Wl, const float* __restrict__ bl,
             const float* __restrict__ Wr, const int* __restrict__ cntS) {
  int tid  = threadIdx.x;
  int lane = tid & 63;
  float4 wl[16], wr[16];
  const float4* Wl4 = (const float4*)(Wl + (size_t)lane * D);
  const float4* Wr4 = (const float4*)(Wr + (size_t)lane * D);
#pragma unroll
  for (int i = 0; i < 16; i++) { wl[i] = Wl4[i]; wr[i] = Wr4[i]; }
  float bias = bl[lane];

  int wid = (blockIdx.x * blockDim.x + tid) >> 6;
  int nw  = (gridDim.x * blockDim.x) >> 6;
  for (int sl = wid; sl < CAP; sl += nw) {
    int shard = sl >> 8, idx = sl & (SEG - 1);
    int nval = cntS[shard * CPAD];
    if (idx >= (nval > SEG ? SEG : nval)) continue;   // wave-uniform
    int v   = nodelist[sl];
    int deg = degC[sl];
    int n   = deg < MAXDEG ? deg : MAXDEG;
    int myid = bucket[sl * MAXDEG + lane];            // lane's bucket entry
    float a0 = 0.f, a1 = 0.f, a2 = 0.f, a3 = 0.f;
    int i = 0;
    for (; i + 4 <= n; i += 4) {
      int s0 = __shfl(myid, i), s1 = __shfl(myid, i + 1);
      int s2 = __shfl(myid, i + 2), s3 = __shfl(myid, i + 3);
      a0 += x[(size_t)s0 * D + lane];
      a1 += x[(size_t)s1 * D + lane];
      a2 += x[(size_t)s2 * D + lane];
      a3 += x[(size_t)s3 * D + lane];
    }
    for (; i < n; i++) {
      int s = __shfl(myid, i);
      a0 += x[(size_t)s * D + lane];
    }
    float dg = (float)deg;
    if (dg < 1.f) dg = 1.f;
    float m  = ((a0 + a1) + (a2 + a3)) / dg;
    float xv = x[(size_t)v * D + lane];
    float h0 = 0.f, hh1 = 0.f, h2 = 0.f, h3 = 0.f;
#pragma unroll
    for (int k = 0; k < D; k += 2) {
      float mk0 = __shfl(m, k);
      float xk0 = __shfl(xv, k);
      float mk1 = __shfl(m, k + 1);
      float xk1 = __shfl(xv, k + 1);
      float c0 = ((const float*)&wl[k >> 2])[k & 3];
      float d0 = ((const float*)&wr[k >> 2])[k & 3];
      float c1 = ((const float*)&wl[(k + 1) >> 2])[(k + 1) & 3];
      float d1 = ((const float*)&wr[(k + 1) >> 2])[(k + 1) & 3];
      h0  += c0 * mk0;
      hh1 += d0 * xk0;
      h2  += c1 * mk1;
      h3  += d1 * xk1;
    }
    float h = bias + ((h0 + h2) + (hh1 + h3));
    h1out[(size_t)sl * D + lane] = fmaxf(h, 0.f);
  }
}

// Center-edge list: agg2[graph(dst)] += h1[slot(src)].
__global__ void k_agg1(const int2* __restrict__ elist, const int* __restrict__ slot,
                       const float* __restrict__ h1, float* __restrict__ agg2,
                       const int* __restrict__ cntE) {
  int lane = threadIdx.x & 63;
  int wid  = (blockIdx.x * blockDim.x + threadIdx.x) >> 6;
  int nw   = (gridDim.x * blockDim.x) >> 6;
  for (int t = wid; t < CAP; t += nw) {
    int shard = t >> 8, idx = t & (SEG - 1);
    int n = cntE[shard * CPAD];
    if (idx >= (n > SEG ? SEG : n)) continue;   // wave-uniform
    int2 ed = elist[t];
    int sl = slot[ed.x];
    int g  = ed.y / NPG;
    atomicAdd(&agg2[(size_t)g * D + lane], h1[(size_t)sl * D + lane]);
  }
}

__global__ void k_final(const float* __restrict__ h1, const float* __restrict__ agg2,
                        const int* __restrict__ degC, const int* __restrict__ slot,
                        const int* __restrict__ cpos, const float* __restrict__ Wl2,
                        const float* __restrict__ bl2, const float* __restrict__ Wr2,
                        const float* __restrict__ Wlin, const float* __restrict__ blin,
                        float* __restrict__ out) {
  int lane = threadIdx.x & 63;
  int g = (blockIdx.x * blockDim.x + threadIdx.x) >> 6;
  if (g >= NG) return;
  int c  = g * NPG + cpos[g];
  int sl = slot[c];
  float dg = (float)degC[sl];
  if (dg < 1.f) dg = 1.f;
  float m  = agg2[(size_t)g * D + lane] / dg;
  float hc = h1[(size_t)sl * D + lane];
  float h  = bl2[lane];
#pragma unroll
  for (int k = 0; k < D; k++) {
    h += Wl2[lane * D + k] * __shfl(m, k) + Wr2[lane * D + k] * __shfl(hc, k);
  }
  h = fmaxf(h, 0.f);
  float p = Wlin[lane] * h;
#pragma unroll
  for (int off = 32; off; off >>= 1) p += __shfl_down(p, off);
  if (lane == 0) out[g] = p + blin[0];
}

extern "C" void kernel_launch(void* const* d_in, const int* in_sizes, int n_in,
                              void* d_out, int out_size, void* d_ws, size_t ws_size,
                              hipStream_t stream) {
  const float* x    = (const float*)d_in[0];
  const int*   ei   = (const int*)d_in[1];
  const int*   srcI = ei;          // edge_index[0]
  const int*   dstI = ei + NE;     // edge_index[1]
  const int*   cpos = (const int*)d_in[3];
  const float* Wl1  = (const float*)d_in[4];
  const float* bl1  = (const float*)d_in[5];
  const float* Wr1  = (const float*)d_in[6];
  const float* Wl2  = (const float*)d_in[7];
  const float* bl2  = (const float*)d_in[8];
  const float* Wr2  = (const float*)d_in[9];
  const float* Wlin = (const float*)d_in[10];
  const float* blin = (const float*)d_in[11];
  float* out = (float*)d_out;

  char* ws = (char*)d_ws;
  float*        agg2 = (float*)(ws + OFF_AGG2);
  unsigned int* bmp  = (unsigned int*)(ws + OFF_BMP);
  int*          degC = (int*)(ws + OFF_DEGC);
  int*          cntE = (int*)(ws + OFF_CNTE);
  int*          cntS = (int*)(ws + OFF_CNTS);
  float*        h1   = (float*)(ws + OFF_H1);
  int*          slot = (int*)(ws + OFF_SLOT);
  int*          nlst = (int*)(ws + OFF_NLIST);
  int2*         elst = (int2*)(ws + OFF_ELIST);
  int*          bkt  = (int*)(ws + OFF_BKT);

  hipMemsetAsync(ws + OFF_AGG2, 0, ZERO_BYTES, stream);
  k_mark<<<2048, 256, 0, stream>>>(srcI, dstI, cpos, bmp, elst, cntE);
  k_compact<<<(NN + 255) / 256, 256, 0, stream>>>(bmp, slot, nlst, cntS);
  k_fill<<<2048, 256, 0, stream>>>(srcI, dstI, bmp, slot, bkt, degC);
  k_sage1<<<512, 256, 0, stream>>>(x, nlst, degC, bkt, h1, Wl1, bl1, Wr1, cntS);
  k_agg1<<<256, 256, 0, stream>>>(elst, slot, h1, agg2, cntE);
  k_final<<<(NG * 64 + 255) / 256, 256, 0, stream>>>(h1, agg2, degC, slot, cpos,
                                                     Wl2, bl2, Wr2, Wlin, blin, out);
}